// Round 1
// baseline (238.608 us; speedup 1.0000x reference)
//
#include <hip/hip_runtime.h>

// Problem constants (reference: BATCH=8192, IN_F=2048, OUT_F=2048)
#define M_DIM 8192
#define N_DIM 2048
#define K_DIM 2048
#define LN2F 0.69314718055994530942f
#define BIAS_PHI 0.62013686f  // softplus(1) - ln2 = log((1+e)/2)

typedef _Float16 f16x8 __attribute__((ext_vector_type(8)));
typedef float f32x4 __attribute__((ext_vector_type(4)));

// ---------------------------------------------------------------------------
// Pass 1: phi[b,i] = f16(softplus(x[b,i]) - ln2), vectorized float4 -> 4x f16
// ---------------------------------------------------------------------------
__device__ __forceinline__ float softplus_m_ln2(float v) {
    // numerically stable softplus minus ln2
    return fmaxf(v, 0.0f) + log1pf(expf(-fabsf(v))) - LN2F;
}

__global__ __launch_bounds__(256) void phi_kernel(const float* __restrict__ x,
                                                  _Float16* __restrict__ phi) {
    size_t i = ((size_t)blockIdx.x * blockDim.x + threadIdx.x) * 4;
    float4 v = *(const float4*)(x + i);
    union { _Float16 h[4]; uint2 u; } pk;
    pk.h[0] = (_Float16)softplus_m_ln2(v.x);
    pk.h[1] = (_Float16)softplus_m_ln2(v.y);
    pk.h[2] = (_Float16)softplus_m_ln2(v.z);
    pk.h[3] = (_Float16)softplus_m_ln2(v.w);
    *(uint2*)(phi + i) = pk.u;
}

// ---------------------------------------------------------------------------
// Pass 2: Wh[o,i] = f16(W[o,i]) for i<2048 (N x K row-major);
//         bias[o] = W[o,2048] * (softplus(1)-ln2)
// ---------------------------------------------------------------------------
__global__ __launch_bounds__(256) void wconv_kernel(const float* __restrict__ W,
                                                    _Float16* __restrict__ Wh,
                                                    float* __restrict__ bias) {
    const int o = blockIdx.x;
    const float* row = W + (size_t)o * (K_DIM + 1);
    _Float16* orow = Wh + (size_t)o * K_DIM;
    for (int i = threadIdx.x; i < K_DIM; i += 256)
        orow[i] = (_Float16)row[i];
    if (threadIdx.x == 0)
        bias[o] = row[K_DIM] * BIAS_PHI;
}

// ---------------------------------------------------------------------------
// Pass 3: C[m,n] = sum_k phi[m,k] * Wh[n,k] + bias[n]
// m97-ladder structure: 128x128 tile, BK=32, 4 waves in 2x2, each wave a
// 64x64 patch as 4x4 grid of 16x16x32 f16 MFMAs. Staging via
// global_load_lds width=16 (wave-uniform LDS base + lane*16).
// ---------------------------------------------------------------------------
__global__ __launch_bounds__(256) void kan_gemm(const _Float16* __restrict__ A,  // M x K
                                                const _Float16* __restrict__ B,  // N x K
                                                const float* __restrict__ bias,  // N
                                                float* __restrict__ C) {         // M x N
    __shared__ __align__(16) _Float16 sA[128 * 32];
    __shared__ __align__(16) _Float16 sB[128 * 32];

    const int tid  = threadIdx.x;
    const int lane = tid & 63;
    const int wv   = tid >> 6;          // wave 0..3

    const size_t Arow0 = (size_t)blockIdx.x * 128;
    const size_t Brow0 = (size_t)blockIdx.y * 128;

    // Staging geometry: one global_load_lds (16B/lane) covers 16 rows x 32
    // cols of f16. Lane l -> row (l>>2), col 8*(l&3). 4 waves x 2 issues
    // cover 128 rows.
    const int rS = lane >> 2;
    const int cS = (lane & 3) * 8;

    const _Float16* gA1 = A + (Arow0 + wv * 16 + rS) * (size_t)K_DIM + cS;
    const _Float16* gA2 = gA1 + (size_t)64 * K_DIM;
    const _Float16* gB1 = B + (Brow0 + wv * 16 + rS) * (size_t)K_DIM + cS;
    const _Float16* gB2 = gB1 + (size_t)64 * K_DIM;

    // wave-uniform LDS destinations (chunk wv and chunk wv+4)
    _Float16* sA1 = &sA[wv * 512];
    _Float16* sA2 = &sA[wv * 512 + 2048];
    _Float16* sB1 = &sB[wv * 512];
    _Float16* sB2 = &sB[wv * 512 + 2048];

    // wave position within the 128x128 tile (2x2 waves of 64x64)
    const int wr = (wv >> 1) * 64;
    const int wc = (wv & 1) * 64;
    // MFMA A/B operand addressing: outer idx = lane&15, k = (lane>>4)*8 + j
    const int lr = lane & 15;
    const int kq = (lane >> 4) * 8;

    f32x4 acc[4][4];
#pragma unroll
    for (int i = 0; i < 4; ++i)
#pragma unroll
        for (int j = 0; j < 4; ++j)
            acc[i][j] = (f32x4){0.0f, 0.0f, 0.0f, 0.0f};

    for (int k0 = 0; k0 < K_DIM; k0 += 32) {
        __syncthreads();  // previous iteration's ds_reads done before overwrite
        __builtin_amdgcn_global_load_lds(
            (const __attribute__((address_space(1))) void*)(gA1 + k0),
            (__attribute__((address_space(3))) void*)sA1, 16, 0, 0);
        __builtin_amdgcn_global_load_lds(
            (const __attribute__((address_space(1))) void*)(gA2 + k0),
            (__attribute__((address_space(3))) void*)sA2, 16, 0, 0);
        __builtin_amdgcn_global_load_lds(
            (const __attribute__((address_space(1))) void*)(gB1 + k0),
            (__attribute__((address_space(3))) void*)sB1, 16, 0, 0);
        __builtin_amdgcn_global_load_lds(
            (const __attribute__((address_space(1))) void*)(gB2 + k0),
            (__attribute__((address_space(3))) void*)sB2, 16, 0, 0);
        __syncthreads();  // compiler drains vmcnt(0) before s_barrier

        f16x8 af[4], bfr[4];
#pragma unroll
        for (int mi = 0; mi < 4; ++mi)
            af[mi] = *(const f16x8*)&sA[(wr + mi * 16 + lr) * 32 + kq];
#pragma unroll
        for (int ni = 0; ni < 4; ++ni)
            bfr[ni] = *(const f16x8*)&sB[(wc + ni * 16 + lr) * 32 + kq];

#pragma unroll
        for (int mi = 0; mi < 4; ++mi)
#pragma unroll
            for (int ni = 0; ni < 4; ++ni)
                acc[mi][ni] = __builtin_amdgcn_mfma_f32_16x16x32_f16(
                    af[mi], bfr[ni], acc[mi][ni], 0, 0, 0);
    }

    // Epilogue. C/D layout: col(n) = lane&15, row(m) = (lane>>4)*4 + reg.
    const int crow = (lane >> 4) * 4;
    float bsv[4];
#pragma unroll
    for (int ni = 0; ni < 4; ++ni)
        bsv[ni] = bias[Brow0 + wc + ni * 16 + lr];

#pragma unroll
    for (int mi = 0; mi < 4; ++mi) {
#pragma unroll
        for (int r = 0; r < 4; ++r) {
            float* cp = C + (Arow0 + wr + mi * 16 + crow + r) * (size_t)N_DIM
                        + Brow0 + wc + lr;
#pragma unroll
            for (int ni = 0; ni < 4; ++ni)
                cp[ni * 16] = acc[mi][ni][r] + bsv[ni];
        }
    }
}

// ---------------------------------------------------------------------------
extern "C" void kernel_launch(void* const* d_in, const int* in_sizes, int n_in,
                              void* d_out, int out_size, void* d_ws, size_t ws_size,
                              hipStream_t stream) {
    const float* x = (const float*)d_in[0];   // (8192, 2048) fp32
    const float* W = (const float*)d_in[1];   // (2048, 2049) fp32
    float* out = (float*)d_out;               // (8192, 2048) fp32

    // workspace layout: phi (M*K f16) | Wh (N*K f16) | bias (N f32)  ~42 MB
    char* ws = (char*)d_ws;
    _Float16* phi = (_Float16*)ws;
    _Float16* Wh  = (_Float16*)(ws + (size_t)M_DIM * K_DIM * sizeof(_Float16));
    float* bias   = (float*)(ws + (size_t)M_DIM * K_DIM * sizeof(_Float16)
                                + (size_t)N_DIM * K_DIM * sizeof(_Float16));

    phi_kernel<<<(M_DIM * K_DIM / 4) / 256, 256, 0, stream>>>(x, phi);
    wconv_kernel<<<N_DIM, 256, 0, stream>>>(W, Wh, bias);
    dim3 grid(M_DIM / 128, N_DIM / 128);  // 64 x 16 = 1024 blocks
    kan_gemm<<<grid, 256, 0, stream>>>(phi, Wh, bias, out);
}

// Round 2
// 216.612 us; speedup vs baseline: 1.1015x; 1.1015x over previous
//
#include <hip/hip_runtime.h>

// Problem constants (reference: BATCH=8192, IN_F=2048, OUT_F=2048)
#define M_DIM 8192
#define N_DIM 2048
#define K_DIM 2048
#define LN2F 0.69314718055994530942f
#define LOG2EF 1.44269504088896340736f
#define BIAS_PHI 0.62011451f  // softplus(1) - ln2 = log((1+e)/2)

typedef _Float16 f16x8 __attribute__((ext_vector_type(8)));
typedef float f32x4 __attribute__((ext_vector_type(4)));

// ---------------------------------------------------------------------------
// softplus(x) - ln2 via native v_exp_f32 (2^x) and v_log_f32 (log2):
//   t = x*log2e;  r = (log2(1 + 2^t) - 1) * ln2
// For t >= 24, 2^t dominates (and could overflow for huge x): r = x - ln2.
// For t very negative, 2^t flushes to 0 -> log2(1)=0 -> r = -ln2 (correct).
// ---------------------------------------------------------------------------
__device__ __forceinline__ float softplus_m_ln2(float v) {
    float t = v * LOG2EF;
    float e = __builtin_amdgcn_exp2f(t);
    float r = (__builtin_amdgcn_logf(1.0f + e) - 1.0f) * LN2F;
    return t < 24.0f ? r : v - LN2F;
}

// ---------------------------------------------------------------------------
// Pass 1: phi[b,i] = f16(softplus(x[b,i]) - ln2). 8 elems/thread, 16B store.
// ---------------------------------------------------------------------------
__global__ __launch_bounds__(256) void phi_kernel(const float* __restrict__ x,
                                                  _Float16* __restrict__ phi) {
    size_t i = ((size_t)blockIdx.x * blockDim.x + threadIdx.x) * 8;
    float4 v0 = *(const float4*)(x + i);
    float4 v1 = *(const float4*)(x + i + 4);
    union { _Float16 h[8]; uint4 u; } pk;
    pk.h[0] = (_Float16)softplus_m_ln2(v0.x);
    pk.h[1] = (_Float16)softplus_m_ln2(v0.y);
    pk.h[2] = (_Float16)softplus_m_ln2(v0.z);
    pk.h[3] = (_Float16)softplus_m_ln2(v0.w);
    pk.h[4] = (_Float16)softplus_m_ln2(v1.x);
    pk.h[5] = (_Float16)softplus_m_ln2(v1.y);
    pk.h[6] = (_Float16)softplus_m_ln2(v1.z);
    pk.h[7] = (_Float16)softplus_m_ln2(v1.w);
    *(uint4*)(phi + i) = pk.u;
}

// ---------------------------------------------------------------------------
// Pass 2: Wh[o,i] = f16(W[o,i]) for i<2048 (N x K row-major);
//         bias[o] = W[o,2048] * (softplus(1)-ln2)
// One row per block; thread t handles cols 8t..8t+7, one 16B store.
// (W rows are 2049 floats -> only 4B-aligned, so loads stay scalar.)
// ---------------------------------------------------------------------------
__global__ __launch_bounds__(256) void wconv_kernel(const float* __restrict__ W,
                                                    _Float16* __restrict__ Wh,
                                                    float* __restrict__ bias) {
    const int o = blockIdx.x;
    const float* row = W + (size_t)o * (K_DIM + 1) + threadIdx.x * 8;
    union { _Float16 h[8]; uint4 u; } pk;
#pragma unroll
    for (int j = 0; j < 8; ++j)
        pk.h[j] = (_Float16)row[j];
    *(uint4*)(Wh + (size_t)o * K_DIM + threadIdx.x * 8) = pk.u;
    if (threadIdx.x == 0)
        bias[o] = W[(size_t)o * (K_DIM + 1) + K_DIM] * BIAS_PHI;
}

// ---------------------------------------------------------------------------
// Pass 3: C[m,n] = sum_k phi[m,k] * Wh[n,k] + bias[n]
// m97-ladder structure: 128x128 tile, BK=32, 4 waves in 2x2, each wave a
// 64x64 patch as 4x4 grid of 16x16x32 f16 MFMAs.
//
// LDS bank-conflict fix (R1: 8.4M conflicts = 16 extra cyc/ds_read):
// XOR-swizzle — logical 16B chunk c of row r lives at physical chunk
// c ^ ((r>>1)&3). Staging keeps the fixed lane->base+lane*16 DMA layout and
// instead permutes WHICH global chunk each lane fetches (same 64B segment
// per 4 lanes, coalescing unchanged). Reads apply the same XOR. Bank-quad
// = 4*(r&1) + (c^((r>>1)&3)) is a bijection per 8-lane group -> 0 conflicts.
// ---------------------------------------------------------------------------
__global__ __launch_bounds__(256) void kan_gemm(const _Float16* __restrict__ A,  // M x K
                                                const _Float16* __restrict__ B,  // N x K
                                                const float* __restrict__ bias,  // N
                                                float* __restrict__ C) {         // M x N
    __shared__ __align__(16) _Float16 sA[128 * 32];
    __shared__ __align__(16) _Float16 sB[128 * 32];

    const int tid  = threadIdx.x;
    const int lane = tid & 63;
    const int wv   = tid >> 6;          // wave 0..3

    const size_t Arow0 = (size_t)blockIdx.x * 128;
    const size_t Brow0 = (size_t)blockIdx.y * 128;

    // Staging: lane l covers row (l>>2) of its 16-row group, physical chunk
    // (l&3). It must FETCH logical chunk (l&3) ^ ((row>>1)&3).
    const int rS = lane >> 2;
    const int cS = ((lane & 3) ^ ((lane >> 3) & 3)) * 8;

    const _Float16* gA1 = A + (Arow0 + wv * 16 + rS) * (size_t)K_DIM + cS;
    const _Float16* gA2 = gA1 + (size_t)64 * K_DIM;
    const _Float16* gB1 = B + (Brow0 + wv * 16 + rS) * (size_t)K_DIM + cS;
    const _Float16* gB2 = gB1 + (size_t)64 * K_DIM;

    // wave-uniform LDS destinations (chunk wv and chunk wv+4)
    _Float16* sA1 = &sA[wv * 512];
    _Float16* sA2 = &sA[wv * 512 + 2048];
    _Float16* sB1 = &sB[wv * 512];
    _Float16* sB2 = &sB[wv * 512 + 2048];

    // wave position within the 128x128 tile (2x2 waves of 64x64)
    const int wr = (wv >> 1) * 64;
    const int wc = (wv & 1) * 64;
    // MFMA A/B operand addressing: outer idx = lane&15, logical chunk
    // c = lane>>4 (k = c*8 + j). Swizzled element offset within the row:
    const int lr  = lane & 15;
    const int kqs = (((lane >> 4) ^ ((lr >> 1) & 3))) * 8;

    f32x4 acc[4][4];
#pragma unroll
    for (int i = 0; i < 4; ++i)
#pragma unroll
        for (int j = 0; j < 4; ++j)
            acc[i][j] = (f32x4){0.0f, 0.0f, 0.0f, 0.0f};

    for (int k0 = 0; k0 < K_DIM; k0 += 32) {
        __syncthreads();  // previous iteration's ds_reads done before overwrite
        __builtin_amdgcn_global_load_lds(
            (const __attribute__((address_space(1))) void*)(gA1 + k0),
            (__attribute__((address_space(3))) void*)sA1, 16, 0, 0);
        __builtin_amdgcn_global_load_lds(
            (const __attribute__((address_space(1))) void*)(gA2 + k0),
            (__attribute__((address_space(3))) void*)sA2, 16, 0, 0);
        __builtin_amdgcn_global_load_lds(
            (const __attribute__((address_space(1))) void*)(gB1 + k0),
            (__attribute__((address_space(3))) void*)sB1, 16, 0, 0);
        __builtin_amdgcn_global_load_lds(
            (const __attribute__((address_space(1))) void*)(gB2 + k0),
            (__attribute__((address_space(3))) void*)sB2, 16, 0, 0);
        __syncthreads();  // compiler drains vmcnt(0) before s_barrier

        f16x8 af[4], bfr[4];
#pragma unroll
        for (int mi = 0; mi < 4; ++mi)
            af[mi] = *(const f16x8*)&sA[(wr + mi * 16 + lr) * 32 + kqs];
#pragma unroll
        for (int ni = 0; ni < 4; ++ni)
            bfr[ni] = *(const f16x8*)&sB[(wc + ni * 16 + lr) * 32 + kqs];

#pragma unroll
        for (int mi = 0; mi < 4; ++mi)
#pragma unroll
            for (int ni = 0; ni < 4; ++ni)
                acc[mi][ni] = __builtin_amdgcn_mfma_f32_16x16x32_f16(
                    af[mi], bfr[ni], acc[mi][ni], 0, 0, 0);
    }

    // Epilogue. C/D layout: col(n) = lane&15, row(m) = (lane>>4)*4 + reg.
    const int crow = (lane >> 4) * 4;
    float bsv[4];
#pragma unroll
    for (int ni = 0; ni < 4; ++ni)
        bsv[ni] = bias[Brow0 + wc + ni * 16 + lr];

#pragma unroll
    for (int mi = 0; mi < 4; ++mi) {
#pragma unroll
        for (int r = 0; r < 4; ++r) {
            float* cp = C + (Arow0 + wr + mi * 16 + crow + r) * (size_t)N_DIM
                        + Brow0 + wc + lr;
#pragma unroll
            for (int ni = 0; ni < 4; ++ni)
                cp[ni * 16] = acc[mi][ni][r] + bsv[ni];
        }
    }
}

// ---------------------------------------------------------------------------
extern "C" void kernel_launch(void* const* d_in, const int* in_sizes, int n_in,
                              void* d_out, int out_size, void* d_ws, size_t ws_size,
                              hipStream_t stream) {
    const float* x = (const float*)d_in[0];   // (8192, 2048) fp32
    const float* W = (const float*)d_in[1];   // (2048, 2049) fp32
    float* out = (float*)d_out;               // (8192, 2048) fp32

    // workspace layout: phi (M*K f16) | Wh (N*K f16) | bias (N f32)  ~42 MB
    char* ws = (char*)d_ws;
    _Float16* phi = (_Float16*)ws;
    _Float16* Wh  = (_Float16*)(ws + (size_t)M_DIM * K_DIM * sizeof(_Float16));
    float* bias   = (float*)(ws + (size_t)M_DIM * K_DIM * sizeof(_Float16)
                                + (size_t)N_DIM * K_DIM * sizeof(_Float16));

    phi_kernel<<<(M_DIM * K_DIM / 8) / 256, 256, 0, stream>>>(x, phi);
    wconv_kernel<<<N_DIM, 256, 0, stream>>>(W, Wh, bias);
    dim3 grid(M_DIM / 128, N_DIM / 128);  // 64 x 16 = 1024 blocks
    kan_gemm<<<grid, 256, 0, stream>>>(phi, Wh, bias, out);
}

// Round 3
// 194.654 us; speedup vs baseline: 1.2258x; 1.1128x over previous
//
#include <hip/hip_runtime.h>

// Problem constants (reference: BATCH=8192, IN_F=2048, OUT_F=2048)
#define M_DIM 8192
#define N_DIM 2048
#define K_DIM 2048
#define LN2F 0.69314718055994530942f
#define LOG2EF 1.44269504088896340736f
#define BIAS_PHI 0.62009741f  // softplus(1) - ln2 = log((1+e)/2)

typedef _Float16 f16x8 __attribute__((ext_vector_type(8)));
typedef float f32x4 __attribute__((ext_vector_type(4)));

// ---------------------------------------------------------------------------
// softplus(x) - ln2 via native v_exp_f32 (2^x) and v_log_f32 (log2):
//   t = x*log2e;  r = (log2(1 + 2^t) - 1) * ln2
// t >= 24: 2^t dominates -> r = x - ln2. t << 0: 2^t -> 0 -> r = -ln2 (ok).
// ---------------------------------------------------------------------------
__device__ __forceinline__ float softplus_m_ln2(float v) {
    float t = v * LOG2EF;
    float e = __builtin_amdgcn_exp2f(t);
    float r = (__builtin_amdgcn_logf(1.0f + e) - 1.0f) * LN2F;
    return t < 24.0f ? r : v - LN2F;
}

// ---------------------------------------------------------------------------
// Fused prep: blocks [0, 8192) do phi; blocks [8192, 10240) do W rows.
//   phi[b,i]  = f16(softplus(x[b,i]) - ln2)          (8 elems/thread, 16B st)
//   Wh[o,i]   = f16(W[o,i]) for i<2048 (N x K row-major)
//   bias[o]   = W[o,2048] * (softplus(1)-ln2)
// ---------------------------------------------------------------------------
__global__ __launch_bounds__(256) void prep_kernel(const float* __restrict__ x,
                                                   const float* __restrict__ W,
                                                   _Float16* __restrict__ phi,
                                                   _Float16* __restrict__ Wh,
                                                   float* __restrict__ bias) {
    if (blockIdx.x < 8192) {
        size_t i = ((size_t)blockIdx.x * blockDim.x + threadIdx.x) * 8;
        float4 v0 = *(const float4*)(x + i);
        float4 v1 = *(const float4*)(x + i + 4);
        union { _Float16 h[8]; uint4 u; } pk;
        pk.h[0] = (_Float16)softplus_m_ln2(v0.x);
        pk.h[1] = (_Float16)softplus_m_ln2(v0.y);
        pk.h[2] = (_Float16)softplus_m_ln2(v0.z);
        pk.h[3] = (_Float16)softplus_m_ln2(v0.w);
        pk.h[4] = (_Float16)softplus_m_ln2(v1.x);
        pk.h[5] = (_Float16)softplus_m_ln2(v1.y);
        pk.h[6] = (_Float16)softplus_m_ln2(v1.z);
        pk.h[7] = (_Float16)softplus_m_ln2(v1.w);
        *(uint4*)(phi + i) = pk.u;
    } else {
        const int o = blockIdx.x - 8192;
        const float* row = W + (size_t)o * (K_DIM + 1) + threadIdx.x * 8;
        union { _Float16 h[8]; uint4 u; } pk;
#pragma unroll
        for (int j = 0; j < 8; ++j)
            pk.h[j] = (_Float16)row[j];
        *(uint4*)(Wh + (size_t)o * K_DIM + threadIdx.x * 8) = pk.u;
        if (threadIdx.x == 0)
            bias[o] = W[(size_t)o * (K_DIM + 1) + K_DIM] * BIAS_PHI;
    }
}

// ---------------------------------------------------------------------------
// GEMM: C[m,n] = sum_k phi[m,k] * Wh[n,k] + bias[n]
// 128x128 tile, BK=64 (R3: halves barrier count vs BK=32; 32 KB LDS still
// allows 4 blocks/CU — BK=128's 64 KB was the m132 occupancy cliff).
// 4 waves in 2x2, each wave 64x64 as 4x4 of 16x16x32 f16 MFMAs, 2 k-chunks.
//
// LDS swizzle (row = 64 f16 = 128 B = 8 chunks of 16 B): physical chunk =
// logical chunk ^ (row & 7). DMA keeps fixed lane->base+lane*16 layout;
// each lane FETCHES the permuted global chunk (same 128 B row segment, so
// coalescing is unchanged). Reads apply the same XOR; per 8-lane phase the
// 8 bank-quads are a bijection -> conflict-free (verified R2: 8.4M -> 0
// with the BK=32 variant of this scheme).
// ---------------------------------------------------------------------------
__global__ __launch_bounds__(256) void kan_gemm(const _Float16* __restrict__ A,  // M x K
                                                const _Float16* __restrict__ B,  // N x K
                                                const float* __restrict__ bias,  // N
                                                float* __restrict__ C) {         // M x N
    __shared__ __align__(16) _Float16 sA[128 * 64];
    __shared__ __align__(16) _Float16 sB[128 * 64];

    const int tid  = threadIdx.x;
    const int lane = tid & 63;
    const int wv   = tid >> 6;          // wave 0..3

    const size_t Arow0 = (size_t)blockIdx.x * 128;
    const size_t Brow0 = (size_t)blockIdx.y * 128;

    // Staging: one issue covers 8 rows x 64 cols. Lane l -> row l>>3,
    // physical chunk l&7, fetches logical chunk (l&7)^(l>>3 & 7).
    const int r8 = lane >> 3;
    const int pc = lane & 7;
    const int lc = pc ^ r8;

    const _Float16* gA = A + (Arow0 + wv * 32 + r8) * (size_t)K_DIM + lc * 8;
    const _Float16* gB = B + (Brow0 + wv * 32 + r8) * (size_t)K_DIM + lc * 8;
    _Float16* sAw = &sA[wv * 32 * 64];  // wave's staging region (+ j*8*64)
    _Float16* sBw = &sB[wv * 32 * 64];

    // wave position within the 128x128 tile (2x2 waves of 64x64)
    const int wr = (wv >> 1) * 64;
    const int wc = (wv & 1) * 64;
    // MFMA operand addressing: outer idx = lane&15, logical chunk
    // c = (lane>>4) + 4*kc; physical = c ^ (lr & 7).
    const int lr   = lane & 15;
    const int kph0 = (((lane >> 4)) ^ (lr & 7)) * 8;  // kc=0 elem offset
    // kc=1: logical chunk +4 -> physical offset XOR (4*8)=32 elems

    f32x4 acc[4][4];
#pragma unroll
    for (int i = 0; i < 4; ++i)
#pragma unroll
        for (int j = 0; j < 4; ++j)
            acc[i][j] = (f32x4){0.0f, 0.0f, 0.0f, 0.0f};

    for (int k0 = 0; k0 < K_DIM; k0 += 64) {
        __syncthreads();  // previous iteration's ds_reads done before overwrite
#pragma unroll
        for (int j = 0; j < 4; ++j) {
            __builtin_amdgcn_global_load_lds(
                (const __attribute__((address_space(1))) void*)(gA + k0 + (size_t)j * 8 * K_DIM),
                (__attribute__((address_space(3))) void*)(sAw + j * 8 * 64), 16, 0, 0);
            __builtin_amdgcn_global_load_lds(
                (const __attribute__((address_space(1))) void*)(gB + k0 + (size_t)j * 8 * K_DIM),
                (__attribute__((address_space(3))) void*)(sBw + j * 8 * 64), 16, 0, 0);
        }
        __syncthreads();  // compiler drains vmcnt(0) before s_barrier

#pragma unroll
        for (int kc = 0; kc < 2; ++kc) {
            const int ko = kph0 ^ (kc * 32);
            f16x8 af[4], bfr[4];
#pragma unroll
            for (int mi = 0; mi < 4; ++mi)
                af[mi] = *(const f16x8*)&sA[(wr + mi * 16 + lr) * 64 + ko];
#pragma unroll
            for (int ni = 0; ni < 4; ++ni)
                bfr[ni] = *(const f16x8*)&sB[(wc + ni * 16 + lr) * 64 + ko];

#pragma unroll
            for (int mi = 0; mi < 4; ++mi)
#pragma unroll
                for (int ni = 0; ni < 4; ++ni)
                    acc[mi][ni] = __builtin_amdgcn_mfma_f32_16x16x32_f16(
                        af[mi], bfr[ni], acc[mi][ni], 0, 0, 0);
        }
    }

    // Epilogue. C/D layout: col(n) = lane&15, row(m) = (lane>>4)*4 + reg.
    const int crow = (lane >> 4) * 4;
    float bsv[4];
#pragma unroll
    for (int ni = 0; ni < 4; ++ni)
        bsv[ni] = bias[Brow0 + wc + ni * 16 + lr];

#pragma unroll
    for (int mi = 0; mi < 4; ++mi) {
#pragma unroll
        for (int r = 0; r < 4; ++r) {
            float* cp = C + (Arow0 + wr + mi * 16 + crow + r) * (size_t)N_DIM
                        + Brow0 + wc + lr;
#pragma unroll
            for (int ni = 0; ni < 4; ++ni)
                cp[ni * 16] = acc[mi][ni][r] + bsv[ni];
        }
    }
}

// ---------------------------------------------------------------------------
extern "C" void kernel_launch(void* const* d_in, const int* in_sizes, int n_in,
                              void* d_out, int out_size, void* d_ws, size_t ws_size,
                              hipStream_t stream) {
    const float* x = (const float*)d_in[0];   // (8192, 2048) fp32
    const float* W = (const float*)d_in[1];   // (2048, 2049) fp32
    float* out = (float*)d_out;               // (8192, 2048) fp32

    // workspace layout: phi (M*K f16) | Wh (N*K f16) | bias (N f32)  ~42 MB
    char* ws = (char*)d_ws;
    _Float16* phi = (_Float16*)ws;
    _Float16* Wh  = (_Float16*)(ws + (size_t)M_DIM * K_DIM * sizeof(_Float16));
    float* bias   = (float*)(ws + (size_t)M_DIM * K_DIM * sizeof(_Float16)
                                + (size_t)N_DIM * K_DIM * sizeof(_Float16));

    prep_kernel<<<8192 + 2048, 256, 0, stream>>>(x, W, phi, Wh, bias);
    dim3 grid(M_DIM / 128, N_DIM / 128);  // 64 x 16 = 1024 blocks
    kan_gemm<<<grid, 256, 0, stream>>>(phi, Wh, bias, out);
}